// Round 1
// baseline (93.894 us; speedup 1.0000x reference)
//
#include <hip/hip_runtime.h>

#define NBINS 64

__device__ __forceinline__ void accum_point(float x, float* h, int base) {
    // clip to [-1,1]; u = (x+1)/LAM with 1/LAM = (R-1)/2 = 31.5 exactly
    float s = fminf(fmaxf(x, -1.0f), 1.0f);
    float u = (s + 1.0f) * 31.5f;          // in [0, 63]
    int   b = (int)u;                      // floor (u >= 0)
    float f = u - (float)b;                // frac
    if (f > 0.0f) {                        // exactly-at-center contributes 0 (strict ineqs in ref)
        atomicAdd(&h[base + b], 1.0f - f); // falling lobe of bin b
        if (b + 1 < NBINS)
            atomicAdd(&h[base + b + 1], f); // rising lobe of bin b+1
    }
}

__global__ void hist_kernel(const float* __restrict__ sim,
                            const float* __restrict__ dis,
                            float* __restrict__ gh, int n) {
    __shared__ float h[2 * NBINS];
    for (int i = threadIdx.x; i < 2 * NBINS; i += blockDim.x) h[i] = 0.0f;
    __syncthreads();

    int tid = blockIdx.x * blockDim.x + threadIdx.x;
    int nthreads = gridDim.x * blockDim.x;
    int nvec = n >> 2;
    const float4* sim4 = (const float4*)sim;
    const float4* dis4 = (const float4*)dis;

    for (int i = tid; i < nvec; i += nthreads) {
        float4 s4 = sim4[i];
        float4 d4 = dis4[i];
        accum_point(s4.x, h, 0);
        accum_point(s4.y, h, 0);
        accum_point(s4.z, h, 0);
        accum_point(s4.w, h, 0);
        accum_point(d4.x, h, NBINS);
        accum_point(d4.y, h, NBINS);
        accum_point(d4.z, h, NBINS);
        accum_point(d4.w, h, NBINS);
    }
    // scalar tail (n not divisible by 4)
    for (int i = (nvec << 2) + tid; i < n; i += nthreads) {
        accum_point(sim[i], h, 0);
        accum_point(dis[i], h, NBINS);
    }

    __syncthreads();
    for (int i = threadIdx.x; i < 2 * NBINS; i += blockDim.x) {
        float v = h[i];
        if (v != 0.0f) atomicAdd(&gh[i], v);  // device-scope by default
    }
}

__global__ void final_kernel(const float* __restrict__ gh,
                             float* __restrict__ out, float invN) {
    int lane = threadIdx.x;  // exactly 64 threads = 1 wave
    float hp = gh[lane] * invN;
    float hm = gh[NBINS + lane] * invN;

    // inclusive prefix sum (cumsum) across the 64-lane wave
    float hpc = hp, hmc = hm;
    #pragma unroll
    for (int off = 1; off < 64; off <<= 1) {
        float a = __shfl_up(hpc, off, 64);
        float b = __shfl_up(hmc, off, 64);
        if (lane >= off) { hpc += a; hmc += b; }
    }

    const float q = 0.9f, p = 0.1f;
    float v = q * q * hpc * hm
            - q * p * hpc * hp
            - q * p * hmc * hm
            + p * p * hmc * hp;

    // wave reduction
    #pragma unroll
    for (int off = 32; off >= 1; off >>= 1) v += __shfl_down(v, off, 64);

    if (lane == 0) out[0] = v / 0.64f;  // 1 - 4P + 4P^2 = (1-2P)^2 = 0.64
}

extern "C" void kernel_launch(void* const* d_in, const int* in_sizes, int n_in,
                              void* d_out, int out_size, void* d_ws, size_t ws_size,
                              hipStream_t stream) {
    const float* sim = (const float*)d_in[0];
    const float* dis = (const float*)d_in[1];
    // d_in[2] (dissim2), d_in[3] (margin), d_in[4] (anchor_swap) unused by reference
    int n = in_sizes[0];
    float* gh = (float*)d_ws;

    hipMemsetAsync(gh, 0, 2 * NBINS * sizeof(float), stream);  // ws is poisoned 0xAA each call
    hist_kernel<<<256, 256, 0, stream>>>(sim, dis, gh, n);
    final_kernel<<<1, 64, 0, stream>>>(gh, (float*)d_out, 1.0f / (float)n);
}